// Round 13
// baseline (141.798 us; speedup 1.0000x reference)
//
#include <hip/hip_runtime.h>

// casConv2d: B=1, C=128, H=W=32, OC=128, K=3, pad=1, stride=1.
// L = 1024, CKK = 1152 = 36 exact 32-tap chunks (reference front-pad chunk == 0).
//
// Round-13: SINGLE KERNEL, no intermediate planes, no grid sync, no ws.
// R12's cooperative launch failed at the API level; but the boundary it
// tried to remove can be removed structurally: one block owns 4 pixels and
// computes EVERYTHING for them (all 36 chunk sums x 128 oc -> minmax ->
// quant) with zero inter-block dependency. Costs: W read per block (576 KB,
// L2-resident per XCD, ~147 MB aggregate at L2 BW ~4 us). Deleted: 18.9 MB
// plane write + 18.9 MB cold read + one dispatch boundary + all ws usage.
//
// Mapping: 256 blocks x 256 thr; wave = one pixel (px = t>>6), lane = oc
// pair (2*lane, 2*lane+1). Chunk sums in 72 VGPRs; per-pixel minmax is a
// wave shfl_xor butterfly (no LDS, no barriers); x-column staged in LDS
// once, compute reads are lane-uniform broadcasts (conflict-free).
#define L_     1024
#define CKK_   1152
#define QMAX_  255.0f
#define NCH    36
#define XROW_  1160           // xs row stride (floats); 1160*4 B = 16-aligned

__global__ __launch_bounds__(256) void cas_fused(
    const float* __restrict__ x,      // [128][32][32]
    const float* __restrict__ w,      // [128][1152]
    const float* __restrict__ bias,   // [128]
    float* __restrict__ out)          // [128][1024]
{
    __shared__ __align__(16) float xs[4][XROW_];   // 4 px columns, 18.6 KB

    const int t  = threadIdx.x;
    const int l0 = blockIdx.x * 4;

    // ---- stage 4 x-columns (implicit zero-pad), 18 loads/thread ----
#pragma unroll
    for (int it = 0; it < 18; it++) {
        const int e  = it * 256 + t;          // 0..4607
        const int px = e / 1152;
        const int d  = e - px * 1152;
        const int c  = d / 9, r = d - 9 * c;
        const int kh = r / 3, kw = r - 3 * kh;
        const int l  = l0 + px;
        const int iy = (l >> 5) + kh - 1;
        const int ix = (l & 31) + kw - 1;
        const bool ok = ((unsigned)iy < 32u) & ((unsigned)ix < 32u);
        const int idx = ok ? (c * 1024 + iy * 32 + ix) : 0;
        const float v = x[idx];
        xs[px][d] = ok ? v : 0.f;
    }
    __syncthreads();

    const int px   = t >> 6;                  // wave id == pixel
    const int lane = t & 63;
    const int oc0  = lane * 2, oc1 = oc0 + 1;
    const int l    = l0 + px;

    const float4* wp0 = (const float4*)(w + (size_t)oc0 * CKK_);
    const float4* wp1 = (const float4*)(w + (size_t)oc1 * CKK_);
    const float4* xp  = (const float4*)&xs[px][0];   // wave-uniform base

    // ---- all 36 chunk sums for 2 oc, kept in VGPRs ----
    float cs0[NCH], cs1[NCH];
    for (int j = 0; j < NCH; j++) {
        float a0 = 0.f, b0 = 0.f, a1 = 0.f, b1 = 0.f;
#pragma unroll
        for (int k4 = 0; k4 < 8; k4++) {
            const int o = j * 8 + k4;
            const float4 xv = xp[o];          // broadcast (lane-uniform addr)
            const float4 wa = wp0[o];
            const float4 wb = wp1[o];
            a0 = fmaf(wa.x, xv.x, a0);
            a0 = fmaf(wa.y, xv.y, a0);
            b0 = fmaf(wa.z, xv.z, b0);
            b0 = fmaf(wa.w, xv.w, b0);
            a1 = fmaf(wb.x, xv.x, a1);
            a1 = fmaf(wb.y, xv.y, a1);
            b1 = fmaf(wb.z, xv.z, b1);
            b1 = fmaf(wb.w, xv.w, b1);
        }
        cs0[j] = a0 + b0;
        cs1[j] = a1 + b1;
    }

    // ---- per-pixel min/max over 128 oc: wave butterfly, no LDS ----
    float cv0 = bias[oc0], cv1 = bias[oc1];
#pragma unroll
    for (int j = 0; j < NCH; j++) { cv0 += cs0[j]; cv1 += cs1[j]; }
    float mn = fminf(cv0, cv1), mx = fmaxf(cv0, cv1);
#pragma unroll
    for (int m = 1; m < 64; m <<= 1) {
        mn = fminf(mn, __shfl_xor(mn, m, 64));
        mx = fmaxf(mx, __shfl_xor(mx, m, 64));
    }
    const float sv = (mx - mn) / QMAX_;       // scale (uniform across wave)
    float z = -mn / sv;
    z = fmaxf(z, 0.f);                        // fmaxf(NaN,0)=0 == where(isnan,0)
    z = fminf(z, QMAX_);
    z = truncf(z);                            // .int() truncation
    const float iv = 1.0f / sv;

    // ---- per-chunk fake-quant (rintf == round-half-even), reduce ----
    float q0 = 0.f, q1 = 0.f;
#pragma unroll
    for (int j = 0; j < NCH; j++) {
        float qa = rintf(cs0[j] * iv) + z;
        qa = fminf(fmaxf(qa, 0.f), QMAX_);
        q0 += (qa - z) * sv;
        float qb = rintf(cs1[j] * iv) + z;
        qb = fminf(fmaxf(qb, 0.f), QMAX_);
        q1 += (qb - z) * sv;
    }
    out[(size_t)oc0 * L_ + l] = q0;           // note: bias NOT added to output
    out[(size_t)oc1 * L_ + l] = q1;
}

extern "C" void kernel_launch(void* const* d_in, const int* in_sizes, int n_in,
                              void* d_out, int out_size, void* d_ws, size_t ws_size,
                              hipStream_t stream) {
    const float* x    = (const float*)d_in[0];  // 128*32*32
    const float* w    = (const float*)d_in[1];  // 128*1152
    const float* bias = (const float*)d_in[2];  // 128
    float* out = (float*)d_out;                 // 128*1024
    (void)d_ws; (void)ws_size;                  // no workspace needed

    cas_fused<<<256, 256, 0, stream>>>(x, w, bias, out);
}